// Round 4
// baseline (61.944 us; speedup 1.0000x reference)
//
#include <hip/hip_runtime.h>

#define BOUNDING_PERC 0.05f

// ---------------------------------------------------------------------------
// scatter_inv: inv[pos[j]] = j   (inv pre-filled with -1 via hipMemsetAsync)
// ---------------------------------------------------------------------------
__global__ __launch_bounds__(256) void scatter_inv_kernel(
    const int* __restrict__ pos, int* __restrict__ inv, int nb)
{
    int j = blockIdx.x * blockDim.x + threadIdx.x;
    if (j < nb) inv[pos[j]] = j;
}

// ---------------------------------------------------------------------------
// Fused kernel: per global face g (bb = g/nfaces, f = g%nfaces):
//   acc = dot(kernel[bb,f,:] @ W + bias, source[bb,f,:,:])
//   j = inv[f]; if j >= 0: bounded fixup using ucenters gathers
//   out[g] = result
// One thread per face, 256 faces/block. NOTE: nfaces is NOT divisible by
// 256, so bb/f MUST be computed per-thread (round-3 bug).
// ---------------------------------------------------------------------------
__global__ __launch_bounds__(256) void fused_kernel(
    const float4* __restrict__ k4,    // (b*nfaces) float4's
    const float4* __restrict__ s4,    // (b*nfaces*9/4) float4's
    const float*  __restrict__ W,     // [4][9]
    const float*  __restrict__ bias,  // [9]
    const int*    __restrict__ inv,   // (nfaces) inverse position map, -1 = none
    const float*  __restrict__ uc,    // (b*ncells)
    const int*    __restrict__ own,   // (nb)
    const int*    __restrict__ nei,   // (nb)
    float*        __restrict__ out,   // (b*nfaces)
    int nfaces, int ncells)
{
    __shared__ float s_src[2304];     // 256 faces * 9 f32
    const int tid   = threadIdx.x;
    const int gbase = blockIdx.x << 8;            // global face base
    const int g     = gbase + tid;                // global face index
    const int bb    = g / nfaces;                 // per-thread batch index
    const int f     = g - bb * nfaces;            // per-thread in-batch face

    // Cooperative coalesced stage of source: 576 float4 = 2304 floats
    {
        const float4* src_blk = s4 + ((size_t)gbase * 9) / 4;
        float4* sm4 = reinterpret_cast<float4*>(s_src);
        sm4[tid]       = src_blk[tid];
        sm4[tid + 256] = src_blk[tid + 256];
        if (tid < 64) sm4[tid + 512] = src_blk[tid + 512];
    }

    // Uniform weights -> scalar loads / SGPRs
    float Wr[4][9];
#pragma unroll
    for (int i = 0; i < 4; ++i)
#pragma unroll
        for (int s = 0; s < 9; ++s)
            Wr[i][s] = W[i * 9 + s];
    float br[9];
#pragma unroll
    for (int s = 0; s < 9; ++s) br[s] = bias[s];

    const float4 kv = k4[g];
    const int j = inv[f];                          // coalesced dword

    __syncthreads();

    const float* S = &s_src[tid * 9];
    float acc = 0.0f;
#pragma unroll
    for (int s = 0; s < 9; ++s) {
        float c = br[s];
        c = fmaf(kv.x, Wr[0][s], c);
        c = fmaf(kv.y, Wr[1][s], c);
        c = fmaf(kv.z, Wr[2][s], c);
        c = fmaf(kv.w, Wr[3][s], c);
        acc = fmaf(c, S[s], acc);
    }

    float res = acc;
    if (j >= 0) {
        float o = uc[bb * ncells + own[j]];
        float n = uc[bb * ncells + nei[j]];
        float smax = fmaxf(o, n);
        float smin = fminf(o, n);
        float flux = 0.5f * (o + n);
        float up   = (flux >= 0.0f) ? o : n;
        float hi   = smax + BOUNDING_PERC * fabsf(smax);
        float lo   = smin - BOUNDING_PERC * fabsf(smin);
        bool valid = (acc >= lo) && (acc <= hi);
        res = valid ? acc : up;
    }
    out[g] = res;
}

// ---------------------------------------------------------------------------
// Fallback pass-1/pass-2 (used only if ws_size is too small for inv map)
// ---------------------------------------------------------------------------
__global__ __launch_bounds__(256) void ufaces_kernel(
    const float4* __restrict__ k4, const float4* __restrict__ s4,
    const float* __restrict__ W, const float* __restrict__ bias,
    float* __restrict__ out)
{
    __shared__ float s_src[2304];
    const int tid = threadIdx.x;
    const int base_face = blockIdx.x << 8;
    {
        const float4* src_blk = s4 + ((size_t)base_face * 9) / 4;
        float4* sm4 = reinterpret_cast<float4*>(s_src);
        sm4[tid]       = src_blk[tid];
        sm4[tid + 256] = src_blk[tid + 256];
        if (tid < 64) sm4[tid + 512] = src_blk[tid + 512];
    }
    float Wr[4][9];
#pragma unroll
    for (int i = 0; i < 4; ++i)
#pragma unroll
        for (int s = 0; s < 9; ++s) Wr[i][s] = W[i * 9 + s];
    float br[9];
#pragma unroll
    for (int s = 0; s < 9; ++s) br[s] = bias[s];
    const float4 kv = k4[base_face + tid];
    __syncthreads();
    const float* S = &s_src[tid * 9];
    float acc = 0.0f;
#pragma unroll
    for (int s = 0; s < 9; ++s) {
        float c = br[s];
        c = fmaf(kv.x, Wr[0][s], c);
        c = fmaf(kv.y, Wr[1][s], c);
        c = fmaf(kv.z, Wr[2][s], c);
        c = fmaf(kv.w, Wr[3][s], c);
        acc = fmaf(c, S[s], acc);
    }
    out[base_face + tid] = acc;
}

__global__ __launch_bounds__(256) void bound_kernel(
    const float* __restrict__ uc, const int* __restrict__ pos,
    const int* __restrict__ own, const int* __restrict__ nei,
    float* __restrict__ out, int nb, int nfaces, int ncells, int nbatch)
{
    int idx = blockIdx.x * blockDim.x + threadIdx.x;
    if (idx >= nbatch * nb) return;
    int j  = idx % nb;
    int bb = idx / nb;
    int p = pos[j];
    float uf = out[bb * nfaces + p];
    float o  = uc[bb * ncells + own[j]];
    float n  = uc[bb * ncells + nei[j]];
    float smax = fmaxf(o, n);
    float smin = fminf(o, n);
    float flux = 0.5f * (o + n);
    float up   = (flux >= 0.0f) ? o : n;
    float hi   = smax + BOUNDING_PERC * fabsf(smax);
    float lo   = smin - BOUNDING_PERC * fabsf(smin);
    bool valid = (uf >= lo) && (uf <= hi);
    out[bb * nfaces + p] = valid ? uf : up;
}

extern "C" void kernel_launch(void* const* d_in, const int* in_sizes, int n_in,
                              void* d_out, int out_size, void* d_ws, size_t ws_size,
                              hipStream_t stream)
{
    const float* kernel_in  = (const float*)d_in[0];  // (b, nfaces, 4)
    const float* source     = (const float*)d_in[1];  // (b, nfaces, 3, 3)
    const float* ucenters   = (const float*)d_in[2];  // (b, ncells)
    const float* W          = (const float*)d_in[3];  // (4, 9)
    const float* bias       = (const float*)d_in[4];  // (9,)
    const int*   positions  = (const int*)d_in[5];    // (nb,)
    const int*   owners     = (const int*)d_in[6];    // (nb,)
    const int*   neighbours = (const int*)d_in[7];    // (nb,)
    float*       out        = (float*)d_out;          // (b, nfaces)

    const int b      = 4;
    const int in_dim = 4;
    const int nfaces = in_sizes[0] / (b * in_dim);
    const int ncells = in_sizes[2] / b;
    const int nb     = in_sizes[5];
    const int total_faces = b * nfaces;               // divisible by 256

    if (ws_size >= (size_t)nfaces * sizeof(int)) {
        int* inv = (int*)d_ws;
        // inv[f] = -1
        hipMemsetAsync(inv, 0xFF, (size_t)nfaces * sizeof(int), stream);
        // inv[pos[j]] = j
        scatter_inv_kernel<<<(nb + 255) / 256, 256, 0, stream>>>(positions, inv, nb);
        // fused compute + bound + store
        fused_kernel<<<total_faces / 256, 256, 0, stream>>>(
            (const float4*)kernel_in, (const float4*)source, W, bias,
            inv, ucenters, owners, neighbours, out, nfaces, ncells);
    } else {
        ufaces_kernel<<<total_faces / 256, 256, 0, stream>>>(
            (const float4*)kernel_in, (const float4*)source, W, bias, out);
        int total = b * nb;
        bound_kernel<<<(total + 255) / 256, 256, 0, stream>>>(
            ucenters, positions, owners, neighbours, out, nb, nfaces, ncells, b);
    }
}